// Round 15
// baseline (32.215 us; speedup 1.0000x reference)
//
#include <hip/hip_runtime.h>

#define FLT_MAX_ 3.402823466e+38f

constexpr int HW    = 9216;          // 96*96
constexpr int AOFF  = 4608;          // u32x4 offset of alpha frags in ws
constexpr int CW    = 34;            // staged cols per row (1+32+1 halo)
constexpr int NCELL = 3 * CW;        // 102 cells
constexpr int CSTR  = 36;            // words per cell (32 ch + 4 pad, 16B-aligned chunks)
constexpr int XSW   = NCELL * CSTR;  // 3672 u32 = 14688 B

using bf16x8 = __attribute__((ext_vector_type(8))) short;
using f32x4  = __attribute__((ext_vector_type(4))) float;
using u32x4  = __attribute__((ext_vector_type(4))) unsigned int;

__device__ inline unsigned cvtpk_bf16(float a, float b) {
    unsigned r;
    asm("v_cvt_pk_bf16_f32 %0, %1, %2" : "=v"(r) : "v"(a), "v"(b));
    return r;
}
// exact split: p = hi + lo with hi = bf16(p) (RNE); packed hi & lo for a pair
__device__ inline void split2(float p0, float p1, unsigned &h, unsigned &l) {
    h = cvtpk_bf16(p0, p1);
    const float h0 = __builtin_bit_cast(float, h << 16);
    const float h1 = __builtin_bit_cast(float, h & 0xFFFF0000u);
    l = cvtpk_bf16(p0 - h0, p1 - h1);
}

// ---- prep: weights -> MFMA B-fragments (hi/lo bf16), L2-resident in ws ----
__global__ __launch_bounds__(256)
void prep_w(const float* __restrict__ phi_w, const float* __restrict__ alpha_w,
            u32x4* __restrict__ wsq) {
    const int kb   = blockIdx.x;          // 0..8 = phi tap, 9 = alpha
    const int n    = threadIdx.x >> 6;    // 0..3
    const int lane = threadIdx.x & 63;
    const int lg   = lane >> 4, kk = lane & 15;
    if (kb < 9) {
        float p[8];
        #pragma unroll
        for (int jj = 0; jj < 8; ++jj) {
            const int ch = lg * 8 + jj;
            p[jj] = phi_w[(ch * 9 + kb) * 64 + n * 16 + kk];
        }
        unsigned h0,h1,h2,h3, l0,l1,l2,l3;
        split2(p[0],p[1],h0,l0); split2(p[2],p[3],h1,l1);
        split2(p[4],p[5],h2,l2); split2(p[6],p[7],h3,l3);
        wsq[(kb * 4 + n) * 64 + lane]        = u32x4{h0,h1,h2,h3};
        wsq[2304 + (kb * 4 + n) * 64 + lane] = u32x4{l0,l1,l2,l3};
    } else {
        #pragma unroll
        for (int kblk = 0; kblk < 2; ++kblk) {
            float p[8];
            #pragma unroll
            for (int jj = 0; jj < 8; ++jj) {
                const int k = kblk * 32 + lg * 8 + jj;
                p[jj] = alpha_w[(n * 16 + kk) * 64 + k];   // B[k][c] = alpha_w[c][k]
            }
            unsigned h0,h1,h2,h3, l0,l1,l2,l3;
            split2(p[0],p[1],h0,l0); split2(p[2],p[3],h1,l1);
            split2(p[4],p[5],h2,l2); split2(p[6],p[7],h3,l3);
            wsq[AOFF + (kblk * 4 + n) * 64 + lane]       = u32x4{h0,h1,h2,h3};
            wsq[AOFF + 512 + (kblk * 4 + n) * 64 + lane] = u32x4{l0,l1,l2,l3};
        }
    }
}

__global__ __launch_bounds__(256, 5)   // all 1152 blocks co-resident (4.5/CU needed, 5 allowed)
void sac_fused(const float* __restrict__ x,
               const float* __restrict__ fc1_w, const float* __restrict__ fc1_b,
               const float* __restrict__ alpha_b,
               const float* __restrict__ phi_b,
               const float* __restrict__ bn_g, const float* __restrict__ bn_b,
               const float* __restrict__ bn_m, const float* __restrict__ bn_v,
               const u32x4* __restrict__ wsq,
               float* __restrict__ out)
{
    __shared__ unsigned xs[XSW];          // 14688 B  [cell][ch swizzled] packed [bf16(p)|bf16(res)]
    __shared__ float    h_lds[32 * 65];   //  8320 B  [pos][k]
    __shared__ unsigned cnts[16 * 132];   //  8448 B  [bin][pos*4 + cg/2]
    __shared__ float    phib[32];
    __shared__ float    redP[64];
                                          // total 31840 B -> 5 blocks/CU by LDS

    const int tid  = threadIdx.x;
    const int lane = tid & 63;
    const int w    = __builtin_amdgcn_readfirstlane(tid >> 6);   // 0..3
    const int g    = blockIdx.x;
    const int gs   = (g & 7) * 144 + (g >> 3);   // XCD-contiguous remap (1152 = 8*144)
    const int b    = gs / 288;
    const int rem  = gs - b * 288;
    const int y0   = rem / 3;                    // row 0..95
    const int x0   = (rem - y0 * 3) * 32;        // 0,32,64

    const int p8    = lane & 7;
    const int cg    = lane >> 3;                 // 0..7 (4 ch each)
    const int pos   = w * 8 + p8;                // 0..31
    const int mycol = pos * 4 + (cg >> 1);
    const int np    = (w & 1) * 2;               // n-block pair (0 or 2)

    const float* __restrict__ xb = x + (size_t)b * 32 * HW;

    // ---------------- stage + split x tile (channel-inner, swizzled) ----------------
    #pragma unroll
    for (int i = 0; i < 13; ++i) {
        const int idx = tid + i * 256;
        if (idx < 32 * NCELL) {
            const int ch = idx / NCELL;          // coalesced: consecutive tid -> consecutive col
            const int rm = idx - ch * NCELL;
            const int r2 = rm / CW;
            const int c2 = rm - r2 * CW;
            const int y  = y0 + r2 - 1;
            const int xg = x0 + c2 - 1;
            float p = 0.f;
            if ((unsigned)y < 96u && (unsigned)xg < 96u)
                p = xb[ch * HW + y * 96 + xg];
            const unsigned t  = cvtpk_bf16(p, p);
            const float    hf = __builtin_bit_cast(float, t << 16);
            const int cell = rm;                 // r2*CW + c2
            const int word = cell * CSTR + ((((ch >> 3) ^ (cell & 3)) << 3) | (ch & 7));
            xs[word] = cvtpk_bf16(p - hf, p);    // [31:16]=bf16(p), [15:0]=bf16(res)
        }
    }

    // HOIST: t-GEMM B-fragment prefetch issued at the TOP -> L2 latency hides under stats
    u32x4 pf[2][4];
    pf[0][0] = wsq[(0 * 4 + np) * 64 + lane];
    pf[0][1] = wsq[(0 * 4 + np + 1) * 64 + lane];
    pf[0][2] = wsq[2304 + (0 * 4 + np) * 64 + lane];
    pf[0][3] = wsq[2304 + (0 * 4 + np + 1) * 64 + lane];
    pf[1][0] = wsq[(1 * 4 + np) * 64 + lane];
    pf[1][1] = wsq[(1 * 4 + np + 1) * 64 + lane];
    pf[1][2] = wsq[2304 + (1 * 4 + np) * 64 + lane];
    pf[1][3] = wsq[2304 + (1 * 4 + np + 1) * 64 + lane];

    // zero own histogram column (wave-private; 2 lanes dup-write same 0)
    #pragma unroll
    for (int bi = 0; bi < 16; ++bi) cnts[bi * 132 + mycol] = 0u;
    __syncthreads();                             // B0: xs ready

    // ---------------- stats: 9 x ds_read_b128 ----------------
    float s1 = 0.f, s2 = 0.f, s3 = 0.f, s4 = 0.f;
    float mn = FLT_MAX_, mx = -FLT_MAX_, pj = 0.f;
    #pragma unroll
    for (int dy = 0; dy < 3; ++dy)
        #pragma unroll
        for (int dx = 0; dx < 3; ++dx) {
            const int tap  = dy * 3 + dx;
            const int cell = dy * CW + pos + dx;
            const int base = cell * CSTR + ((((cg >> 1) ^ (cell & 3)) << 3) | ((cg & 1) << 2));
            const u32x4 w4 = *(const u32x4*)&xs[base];
            #pragma unroll
            for (int cc = 0; cc < 4; ++cc) {
                const unsigned u = w4[cc];
                const float hf = __builtin_bit_cast(float, u & 0xFFFF0000u);
                const float lf = __builtin_bit_cast(float, u << 16);
                const float p  = hf + lf;
                const float pp = p * p;
                s1 += p;
                s2 = fmaf(p, p, s2);
                s3 = fmaf(pp, p, s3);
                s4 = fmaf(pp, pp, s4);
                mn = fminf(mn, p);
                mx = fmaxf(mx, p);
                pj = fmaf(p, phi_b[(cg * 4 + cc) * 9 + tap], pj);
            }
        }
    #pragma unroll
    for (int msk = 8; msk < 64; msk <<= 1) {
        s1 += __shfl_xor(s1, msk);
        s2 += __shfl_xor(s2, msk);
        s3 += __shfl_xor(s3, msk);
        s4 += __shfl_xor(s4, msk);
        mn = fminf(mn, __shfl_xor(mn, msk));
        mx = fmaxf(mx, __shfl_xor(mx, msk));
        pj += __shfl_xor(pj, msk);
    }
    if (cg == 0) phib[pos] = pj;

    const float mu   = s1 * (1.0f / 288.0f);
    const float rng  = (mx - mn) + 1e-6f;        // exact: min/max order-free
    const float invr = 1.0f / rng;

    // ---------------- histogram: re-read xs (same addresses -> bit-identical p) ----------------
    #pragma unroll
    for (int dy = 0; dy < 3; ++dy)
        #pragma unroll
        for (int dx = 0; dx < 3; ++dx) {
            const int cell = dy * CW + pos + dx;
            const int base = cell * CSTR + ((((cg >> 1) ^ (cell & 3)) << 3) | ((cg & 1) << 2));
            const u32x4 w4 = *(const u32x4*)&xs[base];
            #pragma unroll
            for (int cc = 0; cc < 4; ++cc) {
                const unsigned u = w4[cc];
                const float hf = __builtin_bit_cast(float, u & 0xFFFF0000u);
                const float lf = __builtin_bit_cast(float, u << 16);
                const float p  = hf + lf;
                const float pn = (p - mn) * invr;
                const int  bi  = (int)(pn * 15.0f);   // provably in [0,15]
                atomicAdd(&cnts[bi * 132 + mycol], 1u);
            }
        }
    asm volatile("s_waitcnt lgkmcnt(0)" ::: "memory");

    // entropy: 2 bins per lane, gather 4 columns each (same-wave data)
    float ent = 0.f;
    #pragma unroll
    for (int e = 0; e < 2; ++e) {
        const int bi = cg * 2 + e;
        const unsigned cnt = cnts[bi * 132 + pos * 4 + 0] + cnts[bi * 132 + pos * 4 + 1]
                           + cnts[bi * 132 + pos * 4 + 2] + cnts[bi * 132 + pos * 4 + 3];
        const float prob = (float)cnt * (1.0f / 288.0f);
        ent -= prob * __logf(prob + 1e-9f);
    }
    #pragma unroll
    for (int msk = 8; msk < 64; msk <<= 1) ent += __shfl_xor(ent, msk);

    // ---------------- moments finalize + h k-slice -> LDS ----------------
    {
        const float e2  = s2 * (1.0f / 288.0f);
        const float e3  = s3 * (1.0f / 288.0f);
        const float e4  = s4 * (1.0f / 288.0f);
        const float mu2 = mu * mu;
        const float var = fmaxf(e2 - mu2, 0.f);
        const float m3  = e3 - 3.f * mu * e2 + 2.f * mu * mu2;
        const float m4  = e4 - 4.f * mu * e3 + 6.f * mu2 * e2 - 3.f * mu2 * mu2;
        const float sig = sqrtf(var + 1e-6f);
        const float inv = 1.0f / (sig + 1e-6f);
        const float inv2 = inv * inv;
        const float gam = m3 * (inv2 * inv);
        const float kap = m4 * (inv2 * inv2) - 3.0f;
        #pragma unroll
        for (int kk2 = 0; kk2 < 8; ++kk2) {
            const int k = cg * 8 + kk2;
            float acc = fc1_b[k];
            acc = fmaf(mu,  fc1_w[k * 5 + 0], acc);
            acc = fmaf(sig, fc1_w[k * 5 + 1], acc);
            acc = fmaf(gam, fc1_w[k * 5 + 2], acc);
            acc = fmaf(kap, fc1_w[k * 5 + 3], acc);
            acc = fmaf(ent, fc1_w[k * 5 + 4], acc);
            h_lds[pos * 65 + k] = fmaxf(acc, 0.f);
        }
    }
    // NO barrier here: the t-GEMM MFMAs need only xs (B0) + pf.  h_lds isn't read
    // until after the tap loop; the barrier moved there so the MFMA stream hides
    // the h-write sync and slow-wave stats tails overlap other waves' matrix work.

    const int m  = w >> 1;
    const int lg = lane >> 4;
    const int kk = lane & 15;
    const int c0 = np * 16 + kk;

    // ======== t-GEMM via MFMA: A = 2 x ds_read_b128/tap + perms, B 2-deep prefetch ========
    {
        const int acol = m * 16 + kk;

        f32x4 acc0 = {0.f, 0.f, 0.f, 0.f};
        f32x4 acc1 = {0.f, 0.f, 0.f, 0.f};

        #pragma unroll
        for (int tap = 0; tap < 9; ++tap) {
            const int dy = tap / 3, dx = tap % 3;    // compile-time
            const u32x4 bh0 = pf[tap & 1][0];
            const u32x4 bh1 = pf[tap & 1][1];
            const u32x4 bl0 = pf[tap & 1][2];
            const u32x4 bl1 = pf[tap & 1][3];
            if (tap < 7) {
                const int t2 = tap + 2;
                pf[tap & 1][0] = wsq[(t2 * 4 + np) * 64 + lane];
                pf[tap & 1][1] = wsq[(t2 * 4 + np + 1) * 64 + lane];
                pf[tap & 1][2] = wsq[2304 + (t2 * 4 + np) * 64 + lane];
                pf[tap & 1][3] = wsq[2304 + (t2 * 4 + np + 1) * 64 + lane];
            }
            const int cell = dy * CW + acol + dx;
            const int base = cell * CSTR + (((lg ^ (cell & 3))) << 3);
            const u32x4 W03 = *(const u32x4*)&xs[base];
            const u32x4 W47 = *(const u32x4*)&xs[base + 4];
            const unsigned ah0 = __builtin_amdgcn_perm(W03[1], W03[0], 0x07060302u);
            const unsigned ah1 = __builtin_amdgcn_perm(W03[3], W03[2], 0x07060302u);
            const unsigned ah2 = __builtin_amdgcn_perm(W47[1], W47[0], 0x07060302u);
            const unsigned ah3 = __builtin_amdgcn_perm(W47[3], W47[2], 0x07060302u);
            const unsigned al0 = __builtin_amdgcn_perm(W03[1], W03[0], 0x05040100u);
            const unsigned al1 = __builtin_amdgcn_perm(W03[3], W03[2], 0x05040100u);
            const unsigned al2 = __builtin_amdgcn_perm(W47[1], W47[0], 0x05040100u);
            const unsigned al3 = __builtin_amdgcn_perm(W47[3], W47[2], 0x05040100u);
            const bf16x8 Ah  = __builtin_bit_cast(bf16x8, u32x4{ah0,ah1,ah2,ah3});
            const bf16x8 Al  = __builtin_bit_cast(bf16x8, u32x4{al0,al1,al2,al3});
            const bf16x8 Bh0 = __builtin_bit_cast(bf16x8, bh0);
            const bf16x8 Bl0 = __builtin_bit_cast(bf16x8, bl0);
            const bf16x8 Bh1 = __builtin_bit_cast(bf16x8, bh1);
            const bf16x8 Bl1 = __builtin_bit_cast(bf16x8, bl1);

            acc0 = __builtin_amdgcn_mfma_f32_16x16x32_bf16(Ah, Bh0, acc0, 0, 0, 0);
            acc0 = __builtin_amdgcn_mfma_f32_16x16x32_bf16(Ah, Bl0, acc0, 0, 0, 0);
            acc0 = __builtin_amdgcn_mfma_f32_16x16x32_bf16(Al, Bh0, acc0, 0, 0, 0);
            acc1 = __builtin_amdgcn_mfma_f32_16x16x32_bf16(Ah, Bh1, acc1, 0, 0, 0);
            acc1 = __builtin_amdgcn_mfma_f32_16x16x32_bf16(Ah, Bl1, acc1, 0, 0, 0);
            acc1 = __builtin_amdgcn_mfma_f32_16x16x32_bf16(Al, Bh1, acc1, 0, 0, 0);
        }

        __syncthreads();                         // B1 (moved): h_lds ready for ALL waves

        // proj partials: C/D row = lg*4+q (pos), col = lane&15 (k)
        const int k0 = np * 16 + kk;
        const int k1 = k0 + 16;
        const int pbr = (m * 16 + lg * 4) * 65;
        float pr0 = acc0[0] * h_lds[pbr + 0 * 65 + k0] + acc1[0] * h_lds[pbr + 0 * 65 + k1];
        float pr1 = acc0[1] * h_lds[pbr + 1 * 65 + k0] + acc1[1] * h_lds[pbr + 1 * 65 + k1];
        float pr2 = acc0[2] * h_lds[pbr + 2 * 65 + k0] + acc1[2] * h_lds[pbr + 2 * 65 + k1];
        float pr3 = acc0[3] * h_lds[pbr + 3 * 65 + k0] + acc1[3] * h_lds[pbr + 3 * 65 + k1];
        #pragma unroll
        for (int msk = 1; msk < 16; msk <<= 1) {
            pr0 += __shfl_xor(pr0, msk);
            pr1 += __shfl_xor(pr1, msk);
            pr2 += __shfl_xor(pr2, msk);
            pr3 += __shfl_xor(pr3, msk);
        }
        if (kk == 0) {
            const int pb = m * 16 + lg * 4;
            redP[(pb + 0) * 2 + (w & 1)] = pr0;
            redP[(pb + 1) * 2 + (w & 1)] = pr1;
            redP[(pb + 2) * 2 + (w & 1)] = pr2;
            redP[(pb + 3) * 2 + (w & 1)] = pr3;
        }
    }

    // prefetch alpha B-frags + constants BEFORE the barrier (latency hides under t-GEMM)
    const u32x4 Abh0_0 = wsq[AOFF + (0 * 4 + np) * 64 + lane];
    const u32x4 Abh1_0 = wsq[AOFF + (0 * 4 + np + 1) * 64 + lane];
    const u32x4 Abl0_0 = wsq[AOFF + 512 + (0 * 4 + np) * 64 + lane];
    const u32x4 Abl1_0 = wsq[AOFF + 512 + (0 * 4 + np + 1) * 64 + lane];
    const u32x4 Abh0_1 = wsq[AOFF + (1 * 4 + np) * 64 + lane];
    const u32x4 Abh1_1 = wsq[AOFF + (1 * 4 + np + 1) * 64 + lane];
    const u32x4 Abl0_1 = wsq[AOFF + 512 + (1 * 4 + np) * 64 + lane];
    const u32x4 Abl1_1 = wsq[AOFF + 512 + (1 * 4 + np + 1) * 64 + lane];
    const float ab0 = alpha_b[c0], ab1 = alpha_b[c0 + 16];
    const float binv0 = bn_g[c0] * rsqrtf(bn_v[c0] + 1e-5f);
    const float binv1 = bn_g[c0 + 16] * rsqrtf(bn_v[c0 + 16] + 1e-5f);
    const float bm0 = bn_m[c0], bb0 = bn_b[c0];
    const float bm1 = bn_m[c0 + 16], bb1 = bn_b[c0 + 16];
    __syncthreads();                             // B2: redP ready

    // ---- proj for this lane's 4 output positions ----
    const int pb4 = m * 16 + lg * 4;
    const float pj0 = redP[(pb4 + 0) * 2] + redP[(pb4 + 0) * 2 + 1] + phib[pb4 + 0];
    const float pj1 = redP[(pb4 + 1) * 2] + redP[(pb4 + 1) * 2 + 1] + phib[pb4 + 1];
    const float pj2 = redP[(pb4 + 2) * 2] + redP[(pb4 + 2) * 2 + 1] + phib[pb4 + 2];
    const float pj3 = redP[(pb4 + 3) * 2] + redP[(pb4 + 3) * 2 + 1] + phib[pb4 + 3];

    // ======== alpha via MFMA: A = h (LDS), C initialized to alpha bias ========
    f32x4 ac0 = {ab0, ab0, ab0, ab0};
    f32x4 ac1 = {ab1, ab1, ab1, ab1};
    #pragma unroll
    for (int kblk = 0; kblk < 2; ++kblk) {
        const float* hp = &h_lds[(m * 16 + kk) * 65 + kblk * 32 + lg * 8];
        const float h0 = hp[0], h1 = hp[1], h2 = hp[2], h3 = hp[3];
        const float h4 = hp[4], h5 = hp[5], h6 = hp[6], h7 = hp[7];
        unsigned ah0,ah1,ah2,ah3, al0,al1,al2,al3;
        split2(h0,h1,ah0,al0); split2(h2,h3,ah1,al1);
        split2(h4,h5,ah2,al2); split2(h6,h7,ah3,al3);
        const bf16x8 Ah = __builtin_bit_cast(bf16x8, u32x4{ah0,ah1,ah2,ah3});
        const bf16x8 Al = __builtin_bit_cast(bf16x8, u32x4{al0,al1,al2,al3});
        const bf16x8 Bh0 = __builtin_bit_cast(bf16x8, kblk == 0 ? Abh0_0 : Abh0_1);
        const bf16x8 Bl0 = __builtin_bit_cast(bf16x8, kblk == 0 ? Abl0_0 : Abl0_1);
        const bf16x8 Bh1 = __builtin_bit_cast(bf16x8, kblk == 0 ? Abh1_0 : Abh1_1);
        const bf16x8 Bl1 = __builtin_bit_cast(bf16x8, kblk == 0 ? Abl1_0 : Abl1_1);
        ac0 = __builtin_amdgcn_mfma_f32_16x16x32_bf16(Ah, Bh0, ac0, 0, 0, 0);
        ac0 = __builtin_amdgcn_mfma_f32_16x16x32_bf16(Ah, Bl0, ac0, 0, 0, 0);
        ac0 = __builtin_amdgcn_mfma_f32_16x16x32_bf16(Al, Bh0, ac0, 0, 0, 0);
        ac1 = __builtin_amdgcn_mfma_f32_16x16x32_bf16(Ah, Bh1, ac1, 0, 0, 0);
        ac1 = __builtin_amdgcn_mfma_f32_16x16x32_bf16(Ah, Bl1, ac1, 0, 0, 0);
        ac1 = __builtin_amdgcn_mfma_f32_16x16x32_bf16(Al, Bh1, ac1, 0, 0, 0);
    }

    // ---- epilogue: BN + SiLU, 2 channels x 4 consecutive cols ----
    const size_t obase = (size_t)(b * 64) * HW + (size_t)y0 * 96 + x0 + m * 16 + lg * 4;
    {
        const float o0 = ac0[0] * pj0, o1 = ac0[1] * pj1;
        const float o2 = ac0[2] * pj2, o3 = ac0[3] * pj3;
        const float y0v = (o0 - bm0) * binv0 + bb0;
        const float y1v = (o1 - bm0) * binv0 + bb0;
        const float y2v = (o2 - bm0) * binv0 + bb0;
        const float y3v = (o3 - bm0) * binv0 + bb0;
        f32x4 sv;
        sv[0] = __fdividef(y0v, 1.0f + __expf(-y0v));
        sv[1] = __fdividef(y1v, 1.0f + __expf(-y1v));
        sv[2] = __fdividef(y2v, 1.0f + __expf(-y2v));
        sv[3] = __fdividef(y3v, 1.0f + __expf(-y3v));
        *(f32x4*)&out[obase + (size_t)c0 * HW] = sv;
    }
    {
        const float o0 = ac1[0] * pj0, o1 = ac1[1] * pj1;
        const float o2 = ac1[2] * pj2, o3 = ac1[3] * pj3;
        const float y0v = (o0 - bm1) * binv1 + bb1;
        const float y1v = (o1 - bm1) * binv1 + bb1;
        const float y2v = (o2 - bm1) * binv1 + bb1;
        const float y3v = (o3 - bm1) * binv1 + bb1;
        f32x4 sv;
        sv[0] = __fdividef(y0v, 1.0f + __expf(-y0v));
        sv[1] = __fdividef(y1v, 1.0f + __expf(-y1v));
        sv[2] = __fdividef(y2v, 1.0f + __expf(-y2v));
        sv[3] = __fdividef(y3v, 1.0f + __expf(-y3v));
        *(f32x4*)&out[obase + (size_t)(c0 + 16) * HW] = sv;
    }
}

extern "C" void kernel_launch(void* const* d_in, const int* in_sizes, int n_in,
                              void* d_out, int out_size, void* d_ws, size_t ws_size,
                              hipStream_t stream) {
    const float* x   = (const float*)d_in[0];
    const float* f1w = (const float*)d_in[1];
    const float* f1b = (const float*)d_in[2];
    const float* aw  = (const float*)d_in[3];
    const float* ab  = (const float*)d_in[4];
    const float* pw  = (const float*)d_in[5];
    const float* pb  = (const float*)d_in[6];
    const float* bg  = (const float*)d_in[7];
    const float* bb  = (const float*)d_in[8];
    const float* bm  = (const float*)d_in[9];
    const float* bv  = (const float*)d_in[10];

    u32x4* wsq = (u32x4*)d_ws;   // 90112 B used

    prep_w<<<dim3(10), dim3(256), 0, stream>>>(pw, aw, wsq);
    sac_fused<<<dim3(1152), dim3(256), 0, stream>>>(
        x, f1w, f1b, ab, pb, bg, bb, bm, bv, wsq, (float*)d_out);
}

// Round 16
// 29.903 us; speedup vs baseline: 1.0773x; 1.0773x over previous
//
#include <hip/hip_runtime.h>

#define FLT_MAX_ 3.402823466e+38f

constexpr int HW    = 9216;          // 96*96
constexpr int AOFF  = 4608;          // u32x4 offset of alpha frags in ws
constexpr int CW    = 34;            // staged cols per row (1+32+1 halo)
constexpr int NCELL = 3 * CW;        // 102 cells
constexpr int CSTR  = 36;            // words per cell (32 ch + 4 pad, 16B-aligned chunks)
constexpr int XSW   = NCELL * CSTR;  // 3672 u32 = 14688 B

using bf16x8 = __attribute__((ext_vector_type(8))) short;
using f32x4  = __attribute__((ext_vector_type(4))) float;
using u32x4  = __attribute__((ext_vector_type(4))) unsigned int;

__device__ inline unsigned cvtpk_bf16(float a, float b) {
    unsigned r;
    asm("v_cvt_pk_bf16_f32 %0, %1, %2" : "=v"(r) : "v"(a), "v"(b));
    return r;
}
// exact split: p = hi + lo with hi = bf16(p) (RNE); packed hi & lo for a pair
__device__ inline void split2(float p0, float p1, unsigned &h, unsigned &l) {
    h = cvtpk_bf16(p0, p1);
    const float h0 = __builtin_bit_cast(float, h << 16);
    const float h1 = __builtin_bit_cast(float, h & 0xFFFF0000u);
    l = cvtpk_bf16(p0 - h0, p1 - h1);
}

// ---- prep: weights -> MFMA B-fragments (hi/lo bf16), L2-resident in ws ----
__global__ __launch_bounds__(256)
void prep_w(const float* __restrict__ phi_w, const float* __restrict__ alpha_w,
            u32x4* __restrict__ wsq) {
    const int kb   = blockIdx.x;          // 0..8 = phi tap, 9 = alpha
    const int n    = threadIdx.x >> 6;    // 0..3
    const int lane = threadIdx.x & 63;
    const int lg   = lane >> 4, kk = lane & 15;
    if (kb < 9) {
        float p[8];
        #pragma unroll
        for (int jj = 0; jj < 8; ++jj) {
            const int ch = lg * 8 + jj;
            p[jj] = phi_w[(ch * 9 + kb) * 64 + n * 16 + kk];
        }
        unsigned h0,h1,h2,h3, l0,l1,l2,l3;
        split2(p[0],p[1],h0,l0); split2(p[2],p[3],h1,l1);
        split2(p[4],p[5],h2,l2); split2(p[6],p[7],h3,l3);
        wsq[(kb * 4 + n) * 64 + lane]        = u32x4{h0,h1,h2,h3};
        wsq[2304 + (kb * 4 + n) * 64 + lane] = u32x4{l0,l1,l2,l3};
    } else {
        #pragma unroll
        for (int kblk = 0; kblk < 2; ++kblk) {
            float p[8];
            #pragma unroll
            for (int jj = 0; jj < 8; ++jj) {
                const int k = kblk * 32 + lg * 8 + jj;
                p[jj] = alpha_w[(n * 16 + kk) * 64 + k];   // B[k][c] = alpha_w[c][k]
            }
            unsigned h0,h1,h2,h3, l0,l1,l2,l3;
            split2(p[0],p[1],h0,l0); split2(p[2],p[3],h1,l1);
            split2(p[4],p[5],h2,l2); split2(p[6],p[7],h3,l3);
            wsq[AOFF + (kblk * 4 + n) * 64 + lane]       = u32x4{h0,h1,h2,h3};
            wsq[AOFF + 512 + (kblk * 4 + n) * 64 + lane] = u32x4{l0,l1,l2,l3};
        }
    }
}

__global__ __launch_bounds__(256, 5)   // 5 blocks/CU: all 1152 blocks co-resident, ~102 VGPR budget
void sac_fused(const float* __restrict__ x,
               const float* __restrict__ fc1_w, const float* __restrict__ fc1_b,
               const float* __restrict__ alpha_b,
               const float* __restrict__ phi_b,
               const float* __restrict__ bn_g, const float* __restrict__ bn_b,
               const float* __restrict__ bn_m, const float* __restrict__ bn_v,
               const u32x4* __restrict__ wsq,
               float* __restrict__ out)
{
    __shared__ unsigned xs[XSW];          // 14688 B  [cell][ch swizzled] packed [bf16(p)|bf16(res)]
    __shared__ float    h_lds[32 * 65];   //  8320 B  [pos][k]
    __shared__ unsigned cnts[16 * 132];   //  8448 B  [bin][pos*4 + cg/2]
    __shared__ float    phib[32];
    __shared__ float    redP[64];
                                          // total 31840 B -> 5 blocks/CU by LDS

    const int tid  = threadIdx.x;
    const int lane = tid & 63;
    const int w    = __builtin_amdgcn_readfirstlane(tid >> 6);   // 0..3
    const int g    = blockIdx.x;
    const int gs   = (g & 7) * 144 + (g >> 3);   // XCD-contiguous remap (1152 = 8*144)
    const int b    = gs / 288;
    const int rem  = gs - b * 288;
    const int y0   = rem / 3;                    // row 0..95
    const int x0   = (rem - y0 * 3) * 32;        // 0,32,64

    const int p8    = lane & 7;
    const int cg    = lane >> 3;                 // 0..7 (4 ch each)
    const int pos   = w * 8 + p8;                // 0..31
    const int mycol = pos * 4 + (cg >> 1);

    const float* __restrict__ xb = x + (size_t)b * 32 * HW;

    // ---------------- stage + split x tile (channel-inner, swizzled) ----------------
    #pragma unroll
    for (int i = 0; i < 13; ++i) {
        const int idx = tid + i * 256;
        if (idx < 32 * NCELL) {
            const int ch = idx / NCELL;          // coalesced: consecutive tid -> consecutive col
            const int rm = idx - ch * NCELL;
            const int r2 = rm / CW;
            const int c2 = rm - r2 * CW;
            const int y  = y0 + r2 - 1;
            const int xg = x0 + c2 - 1;
            float p = 0.f;
            if ((unsigned)y < 96u && (unsigned)xg < 96u)
                p = xb[ch * HW + y * 96 + xg];
            const unsigned t  = cvtpk_bf16(p, p);
            const float    hf = __builtin_bit_cast(float, t << 16);
            const int cell = rm;                 // r2*CW + c2
            const int word = cell * CSTR + ((((ch >> 3) ^ (cell & 3)) << 3) | (ch & 7));
            xs[word] = cvtpk_bf16(p - hf, p);    // [31:16]=bf16(p), [15:0]=bf16(res)
        }
    }
    // zero own histogram column (wave-private; 2 lanes dup-write same 0)
    #pragma unroll
    for (int bi = 0; bi < 16; ++bi) cnts[bi * 132 + mycol] = 0u;
    __syncthreads();                             // B0: xs ready

    // ---------------- stats: 9 x ds_read_b128 (no register cache: occupancy > reg reuse) ----------------
    float s1 = 0.f, s2 = 0.f, s3 = 0.f, s4 = 0.f;
    float mn = FLT_MAX_, mx = -FLT_MAX_, pj = 0.f;
    #pragma unroll
    for (int dy = 0; dy < 3; ++dy)
        #pragma unroll
        for (int dx = 0; dx < 3; ++dx) {
            const int tap  = dy * 3 + dx;
            const int cell = dy * CW + pos + dx;
            const int base = cell * CSTR + ((((cg >> 1) ^ (cell & 3)) << 3) | ((cg & 1) << 2));
            const u32x4 w4 = *(const u32x4*)&xs[base];
            #pragma unroll
            for (int cc = 0; cc < 4; ++cc) {
                const unsigned u = w4[cc];
                const float hf = __builtin_bit_cast(float, u & 0xFFFF0000u);
                const float lf = __builtin_bit_cast(float, u << 16);
                const float p  = hf + lf;
                const float pp = p * p;
                s1 += p;
                s2 = fmaf(p, p, s2);
                s3 = fmaf(pp, p, s3);
                s4 = fmaf(pp, pp, s4);
                mn = fminf(mn, p);
                mx = fmaxf(mx, p);
                pj = fmaf(p, phi_b[(cg * 4 + cc) * 9 + tap], pj);
            }
        }
    #pragma unroll
    for (int msk = 8; msk < 64; msk <<= 1) {
        s1 += __shfl_xor(s1, msk);
        s2 += __shfl_xor(s2, msk);
        s3 += __shfl_xor(s3, msk);
        s4 += __shfl_xor(s4, msk);
        mn = fminf(mn, __shfl_xor(mn, msk));
        mx = fmaxf(mx, __shfl_xor(mx, msk));
        pj += __shfl_xor(pj, msk);
    }
    if (cg == 0) phib[pos] = pj;

    const float mu   = s1 * (1.0f / 288.0f);
    const float rng  = (mx - mn) + 1e-6f;        // exact: min/max order-free
    const float invr = 1.0f / rng;

    // ---------------- histogram: re-read xs (same addresses -> bit-identical p) ----------------
    #pragma unroll
    for (int dy = 0; dy < 3; ++dy)
        #pragma unroll
        for (int dx = 0; dx < 3; ++dx) {
            const int cell = dy * CW + pos + dx;
            const int base = cell * CSTR + ((((cg >> 1) ^ (cell & 3)) << 3) | ((cg & 1) << 2));
            const u32x4 w4 = *(const u32x4*)&xs[base];
            #pragma unroll
            for (int cc = 0; cc < 4; ++cc) {
                const unsigned u = w4[cc];
                const float hf = __builtin_bit_cast(float, u & 0xFFFF0000u);
                const float lf = __builtin_bit_cast(float, u << 16);
                const float p  = hf + lf;
                const float pn = (p - mn) * invr;
                const int  bi  = (int)(pn * 15.0f);   // provably in [0,15]
                atomicAdd(&cnts[bi * 132 + mycol], 1u);
            }
        }
    asm volatile("s_waitcnt lgkmcnt(0)" ::: "memory");

    // entropy: 2 bins per lane, gather 4 columns each (same-wave data)
    float ent = 0.f;
    #pragma unroll
    for (int e = 0; e < 2; ++e) {
        const int bi = cg * 2 + e;
        const unsigned cnt = cnts[bi * 132 + pos * 4 + 0] + cnts[bi * 132 + pos * 4 + 1]
                           + cnts[bi * 132 + pos * 4 + 2] + cnts[bi * 132 + pos * 4 + 3];
        const float prob = (float)cnt * (1.0f / 288.0f);
        ent -= prob * __logf(prob + 1e-9f);
    }
    #pragma unroll
    for (int msk = 8; msk < 64; msk <<= 1) ent += __shfl_xor(ent, msk);

    // ---------------- moments finalize + h k-slice -> LDS ----------------
    {
        const float e2  = s2 * (1.0f / 288.0f);
        const float e3  = s3 * (1.0f / 288.0f);
        const float e4  = s4 * (1.0f / 288.0f);
        const float mu2 = mu * mu;
        const float var = fmaxf(e2 - mu2, 0.f);
        const float m3  = e3 - 3.f * mu * e2 + 2.f * mu * mu2;
        const float m4  = e4 - 4.f * mu * e3 + 6.f * mu2 * e2 - 3.f * mu2 * mu2;
        const float sig = sqrtf(var + 1e-6f);
        const float inv = 1.0f / (sig + 1e-6f);
        const float inv2 = inv * inv;
        const float gam = m3 * (inv2 * inv);
        const float kap = m4 * (inv2 * inv2) - 3.0f;
        #pragma unroll
        for (int kk2 = 0; kk2 < 8; ++kk2) {
            const int k = cg * 8 + kk2;
            float acc = fc1_b[k];
            acc = fmaf(mu,  fc1_w[k * 5 + 0], acc);
            acc = fmaf(sig, fc1_w[k * 5 + 1], acc);
            acc = fmaf(gam, fc1_w[k * 5 + 2], acc);
            acc = fmaf(kap, fc1_w[k * 5 + 3], acc);
            acc = fmaf(ent, fc1_w[k * 5 + 4], acc);
            h_lds[pos * 65 + k] = fmaxf(acc, 0.f);
        }
    }
    __syncthreads();                             // B1: h + phib ready

    const int m  = w >> 1;
    const int np = (w & 1) * 2;
    const int lg = lane >> 4;
    const int kk = lane & 15;
    const int c0 = np * 16 + kk;

    // ======== t-GEMM via MFMA: A = 2 x ds_read_b128/tap + perms, B 2-deep prefetch ========
    {
        const int acol = m * 16 + kk;

        f32x4 acc0 = {0.f, 0.f, 0.f, 0.f};
        f32x4 acc1 = {0.f, 0.f, 0.f, 0.f};

        u32x4 pf[2][4];
        pf[0][0] = wsq[(0 * 4 + np) * 64 + lane];
        pf[0][1] = wsq[(0 * 4 + np + 1) * 64 + lane];
        pf[0][2] = wsq[2304 + (0 * 4 + np) * 64 + lane];
        pf[0][3] = wsq[2304 + (0 * 4 + np + 1) * 64 + lane];
        pf[1][0] = wsq[(1 * 4 + np) * 64 + lane];
        pf[1][1] = wsq[(1 * 4 + np + 1) * 64 + lane];
        pf[1][2] = wsq[2304 + (1 * 4 + np) * 64 + lane];
        pf[1][3] = wsq[2304 + (1 * 4 + np + 1) * 64 + lane];

        #pragma unroll
        for (int tap = 0; tap < 9; ++tap) {
            const int dy = tap / 3, dx = tap % 3;    // compile-time
            const u32x4 bh0 = pf[tap & 1][0];
            const u32x4 bh1 = pf[tap & 1][1];
            const u32x4 bl0 = pf[tap & 1][2];
            const u32x4 bl1 = pf[tap & 1][3];
            if (tap < 7) {
                const int t2 = tap + 2;
                pf[tap & 1][0] = wsq[(t2 * 4 + np) * 64 + lane];
                pf[tap & 1][1] = wsq[(t2 * 4 + np + 1) * 64 + lane];
                pf[tap & 1][2] = wsq[2304 + (t2 * 4 + np) * 64 + lane];
                pf[tap & 1][3] = wsq[2304 + (t2 * 4 + np + 1) * 64 + lane];
            }
            const int cell = dy * CW + acol + dx;
            const int base = cell * CSTR + (((lg ^ (cell & 3))) << 3);
            const u32x4 W03 = *(const u32x4*)&xs[base];
            const u32x4 W47 = *(const u32x4*)&xs[base + 4];
            const unsigned ah0 = __builtin_amdgcn_perm(W03[1], W03[0], 0x07060302u);
            const unsigned ah1 = __builtin_amdgcn_perm(W03[3], W03[2], 0x07060302u);
            const unsigned ah2 = __builtin_amdgcn_perm(W47[1], W47[0], 0x07060302u);
            const unsigned ah3 = __builtin_amdgcn_perm(W47[3], W47[2], 0x07060302u);
            const unsigned al0 = __builtin_amdgcn_perm(W03[1], W03[0], 0x05040100u);
            const unsigned al1 = __builtin_amdgcn_perm(W03[3], W03[2], 0x05040100u);
            const unsigned al2 = __builtin_amdgcn_perm(W47[1], W47[0], 0x05040100u);
            const unsigned al3 = __builtin_amdgcn_perm(W47[3], W47[2], 0x05040100u);
            const bf16x8 Ah  = __builtin_bit_cast(bf16x8, u32x4{ah0,ah1,ah2,ah3});
            const bf16x8 Al  = __builtin_bit_cast(bf16x8, u32x4{al0,al1,al2,al3});
            const bf16x8 Bh0 = __builtin_bit_cast(bf16x8, bh0);
            const bf16x8 Bl0 = __builtin_bit_cast(bf16x8, bl0);
            const bf16x8 Bh1 = __builtin_bit_cast(bf16x8, bh1);
            const bf16x8 Bl1 = __builtin_bit_cast(bf16x8, bl1);

            acc0 = __builtin_amdgcn_mfma_f32_16x16x32_bf16(Ah, Bh0, acc0, 0, 0, 0);
            acc0 = __builtin_amdgcn_mfma_f32_16x16x32_bf16(Ah, Bl0, acc0, 0, 0, 0);
            acc0 = __builtin_amdgcn_mfma_f32_16x16x32_bf16(Al, Bh0, acc0, 0, 0, 0);
            acc1 = __builtin_amdgcn_mfma_f32_16x16x32_bf16(Ah, Bh1, acc1, 0, 0, 0);
            acc1 = __builtin_amdgcn_mfma_f32_16x16x32_bf16(Ah, Bl1, acc1, 0, 0, 0);
            acc1 = __builtin_amdgcn_mfma_f32_16x16x32_bf16(Al, Bh1, acc1, 0, 0, 0);
        }

        // proj partials: C/D row = lg*4+q (pos), col = lane&15 (k)
        const int k0 = np * 16 + kk;
        const int k1 = k0 + 16;
        const int pbr = (m * 16 + lg * 4) * 65;
        float pr0 = acc0[0] * h_lds[pbr + 0 * 65 + k0] + acc1[0] * h_lds[pbr + 0 * 65 + k1];
        float pr1 = acc0[1] * h_lds[pbr + 1 * 65 + k0] + acc1[1] * h_lds[pbr + 1 * 65 + k1];
        float pr2 = acc0[2] * h_lds[pbr + 2 * 65 + k0] + acc1[2] * h_lds[pbr + 2 * 65 + k1];
        float pr3 = acc0[3] * h_lds[pbr + 3 * 65 + k0] + acc1[3] * h_lds[pbr + 3 * 65 + k1];
        #pragma unroll
        for (int msk = 1; msk < 16; msk <<= 1) {
            pr0 += __shfl_xor(pr0, msk);
            pr1 += __shfl_xor(pr1, msk);
            pr2 += __shfl_xor(pr2, msk);
            pr3 += __shfl_xor(pr3, msk);
        }
        if (kk == 0) {
            const int pb = m * 16 + lg * 4;
            redP[(pb + 0) * 2 + (w & 1)] = pr0;
            redP[(pb + 1) * 2 + (w & 1)] = pr1;
            redP[(pb + 2) * 2 + (w & 1)] = pr2;
            redP[(pb + 3) * 2 + (w & 1)] = pr3;
        }
    }

    // prefetch alpha B-frags + constants BEFORE the barrier (latency hides under t-GEMM)
    const u32x4 Abh0_0 = wsq[AOFF + (0 * 4 + np) * 64 + lane];
    const u32x4 Abh1_0 = wsq[AOFF + (0 * 4 + np + 1) * 64 + lane];
    const u32x4 Abl0_0 = wsq[AOFF + 512 + (0 * 4 + np) * 64 + lane];
    const u32x4 Abl1_0 = wsq[AOFF + 512 + (0 * 4 + np + 1) * 64 + lane];
    const u32x4 Abh0_1 = wsq[AOFF + (1 * 4 + np) * 64 + lane];
    const u32x4 Abh1_1 = wsq[AOFF + (1 * 4 + np + 1) * 64 + lane];
    const u32x4 Abl0_1 = wsq[AOFF + 512 + (1 * 4 + np) * 64 + lane];
    const u32x4 Abl1_1 = wsq[AOFF + 512 + (1 * 4 + np + 1) * 64 + lane];
    const float ab0 = alpha_b[c0], ab1 = alpha_b[c0 + 16];
    const float binv0 = bn_g[c0] * rsqrtf(bn_v[c0] + 1e-5f);
    const float binv1 = bn_g[c0 + 16] * rsqrtf(bn_v[c0 + 16] + 1e-5f);
    const float bm0 = bn_m[c0], bb0 = bn_b[c0];
    const float bm1 = bn_m[c0 + 16], bb1 = bn_b[c0 + 16];
    __syncthreads();                             // B2: redP ready

    // ---- proj for this lane's 4 output positions ----
    const int pb4 = m * 16 + lg * 4;
    const float pj0 = redP[(pb4 + 0) * 2] + redP[(pb4 + 0) * 2 + 1] + phib[pb4 + 0];
    const float pj1 = redP[(pb4 + 1) * 2] + redP[(pb4 + 1) * 2 + 1] + phib[pb4 + 1];
    const float pj2 = redP[(pb4 + 2) * 2] + redP[(pb4 + 2) * 2 + 1] + phib[pb4 + 2];
    const float pj3 = redP[(pb4 + 3) * 2] + redP[(pb4 + 3) * 2 + 1] + phib[pb4 + 3];

    // ======== alpha via MFMA: A = h (LDS), C initialized to alpha bias ========
    f32x4 ac0 = {ab0, ab0, ab0, ab0};
    f32x4 ac1 = {ab1, ab1, ab1, ab1};
    #pragma unroll
    for (int kblk = 0; kblk < 2; ++kblk) {
        const float* hp = &h_lds[(m * 16 + kk) * 65 + kblk * 32 + lg * 8];
        const float h0 = hp[0], h1 = hp[1], h2 = hp[2], h3 = hp[3];
        const float h4 = hp[4], h5 = hp[5], h6 = hp[6], h7 = hp[7];
        unsigned ah0,ah1,ah2,ah3, al0,al1,al2,al3;
        split2(h0,h1,ah0,al0); split2(h2,h3,ah1,al1);
        split2(h4,h5,ah2,al2); split2(h6,h7,ah3,al3);
        const bf16x8 Ah = __builtin_bit_cast(bf16x8, u32x4{ah0,ah1,ah2,ah3});
        const bf16x8 Al = __builtin_bit_cast(bf16x8, u32x4{al0,al1,al2,al3});
        const bf16x8 Bh0 = __builtin_bit_cast(bf16x8, kblk == 0 ? Abh0_0 : Abh0_1);
        const bf16x8 Bl0 = __builtin_bit_cast(bf16x8, kblk == 0 ? Abl0_0 : Abl0_1);
        const bf16x8 Bh1 = __builtin_bit_cast(bf16x8, kblk == 0 ? Abh1_0 : Abh1_1);
        const bf16x8 Bl1 = __builtin_bit_cast(bf16x8, kblk == 0 ? Abl1_0 : Abl1_1);
        ac0 = __builtin_amdgcn_mfma_f32_16x16x32_bf16(Ah, Bh0, ac0, 0, 0, 0);
        ac0 = __builtin_amdgcn_mfma_f32_16x16x32_bf16(Ah, Bl0, ac0, 0, 0, 0);
        ac0 = __builtin_amdgcn_mfma_f32_16x16x32_bf16(Al, Bh0, ac0, 0, 0, 0);
        ac1 = __builtin_amdgcn_mfma_f32_16x16x32_bf16(Ah, Bh1, ac1, 0, 0, 0);
        ac1 = __builtin_amdgcn_mfma_f32_16x16x32_bf16(Ah, Bl1, ac1, 0, 0, 0);
        ac1 = __builtin_amdgcn_mfma_f32_16x16x32_bf16(Al, Bh1, ac1, 0, 0, 0);
    }

    // ---- epilogue: BN + SiLU, 2 channels x 4 consecutive cols ----
    const size_t obase = (size_t)(b * 64) * HW + (size_t)y0 * 96 + x0 + m * 16 + lg * 4;
    {
        const float o0 = ac0[0] * pj0, o1 = ac0[1] * pj1;
        const float o2 = ac0[2] * pj2, o3 = ac0[3] * pj3;
        const float y0v = (o0 - bm0) * binv0 + bb0;
        const float y1v = (o1 - bm0) * binv0 + bb0;
        const float y2v = (o2 - bm0) * binv0 + bb0;
        const float y3v = (o3 - bm0) * binv0 + bb0;
        f32x4 sv;
        sv[0] = __fdividef(y0v, 1.0f + __expf(-y0v));
        sv[1] = __fdividef(y1v, 1.0f + __expf(-y1v));
        sv[2] = __fdividef(y2v, 1.0f + __expf(-y2v));
        sv[3] = __fdividef(y3v, 1.0f + __expf(-y3v));
        *(f32x4*)&out[obase + (size_t)c0 * HW] = sv;
    }
    {
        const float o0 = ac1[0] * pj0, o1 = ac1[1] * pj1;
        const float o2 = ac1[2] * pj2, o3 = ac1[3] * pj3;
        const float y0v = (o0 - bm1) * binv1 + bb1;
        const float y1v = (o1 - bm1) * binv1 + bb1;
        const float y2v = (o2 - bm1) * binv1 + bb1;
        const float y3v = (o3 - bm1) * binv1 + bb1;
        f32x4 sv;
        sv[0] = __fdividef(y0v, 1.0f + __expf(-y0v));
        sv[1] = __fdividef(y1v, 1.0f + __expf(-y1v));
        sv[2] = __fdividef(y2v, 1.0f + __expf(-y2v));
        sv[3] = __fdividef(y3v, 1.0f + __expf(-y3v));
        *(f32x4*)&out[obase + (size_t)(c0 + 16) * HW] = sv;
    }
}

extern "C" void kernel_launch(void* const* d_in, const int* in_sizes, int n_in,
                              void* d_out, int out_size, void* d_ws, size_t ws_size,
                              hipStream_t stream) {
    const float* x   = (const float*)d_in[0];
    const float* f1w = (const float*)d_in[1];
    const float* f1b = (const float*)d_in[2];
    const float* aw  = (const float*)d_in[3];
    const float* ab  = (const float*)d_in[4];
    const float* pw  = (const float*)d_in[5];
    const float* pb  = (const float*)d_in[6];
    const float* bg  = (const float*)d_in[7];
    const float* bb  = (const float*)d_in[8];
    const float* bm  = (const float*)d_in[9];
    const float* bv  = (const float*)d_in[10];

    u32x4* wsq = (u32x4*)d_ws;   // 90112 B used

    prep_w<<<dim3(10), dim3(256), 0, stream>>>(pw, aw, wsq);
    sac_fused<<<dim3(1152), dim3(256), 0, stream>>>(
        x, f1w, f1b, ab, pb, bg, bb, bm, bv, wsq, (float*)d_out);
}